// Round 13
// baseline (608.031 us; speedup 1.0000x reference)
//
#include <hip/hip_runtime.h>
#include <math.h>

#define DIN 18
#define HID 128
#define NEGS 0.2f
#define BN_EPS 1e-5f
#define SCHUNK 2048
#define ET 256          // edge slots per agg tile
#define NB 8            // nodes per agg block

typedef unsigned short ushort_t;
typedef __attribute__((ext_vector_type(8))) short bf16x8;
typedef __attribute__((ext_vector_type(4))) float f32x4;

__device__ __forceinline__ float leaky(float x){ return x >= 0.f ? x : NEGS * x; }

__device__ __forceinline__ float wred_sum(float v){
  #pragma unroll
  for (int off = 32; off; off >>= 1) v += __shfl_xor(v, off);
  return v;
}

__device__ __forceinline__ ushort_t f2bf(float f){
  union { float f; unsigned u; } v; v.f = f;
  unsigned r = v.u + 0x7FFFu + ((v.u >> 16) & 1u);
  return (ushort_t)(r >> 16);
}
__device__ __forceinline__ float bf_lo(unsigned p){ return __uint_as_float(p << 16); }
__device__ __forceinline__ float bf_hi(unsigned p){ return __uint_as_float(p & 0xFFFF0000u); }
__device__ __forceinline__ unsigned packbf(float a, float b){
  return (unsigned)f2bf(a) | ((unsigned)f2bf(b) << 16);
}

__device__ __forceinline__ void gload_lds4(const void* g, void* l){
  __builtin_amdgcn_global_load_lds((const __attribute__((address_space(1))) void*)g,
                                   (__attribute__((address_space(3))) void*)l, 4, 0, 0);
}

// ---------------- CSR build: single atomic pass ----------------
__global__ void k_deg_rank(const int* __restrict__ row, int* __restrict__ deg,
                           int* __restrict__ rank, int E){
  int i = blockIdx.x * blockDim.x + threadIdx.x;
  if (i < E) rank[i] = atomicAdd(&deg[row[i]], 1);
}

__global__ void k_scan1(const int* __restrict__ deg, int* __restrict__ bsum, int n){
  __shared__ int wtot[4];
  int tid = threadIdx.x, lane = tid & 63, wid = tid >> 6;
  int base = blockIdx.x * SCHUNK + tid * 8;
  int acc = 0;
  #pragma unroll
  for (int j = 0; j < 8; ++j){
    int i = base + j;
    if (i < n) acc += deg[i];
  }
  #pragma unroll
  for (int off = 32; off; off >>= 1) acc += __shfl_xor(acc, off);
  if (lane == 0) wtot[wid] = acc;
  __syncthreads();
  if (tid == 0) bsum[blockIdx.x] = wtot[0] + wtot[1] + wtot[2] + wtot[3];
}

__global__ void k_scan2(int* __restrict__ bsum, int nb){
  int lane = threadIdx.x;
  int carry = 0;
  for (int base = 0; base < nb; base += 64){
    int i = base + lane;
    int v = (i < nb) ? bsum[i] : 0;
    #pragma unroll
    for (int off = 1; off < 64; off <<= 1){
      int u = __shfl_up(v, off);
      if (lane >= off) v += u;
    }
    if (i < nb) bsum[i] = v + carry;
    carry += __shfl(v, 63);
  }
}

__global__ void k_scan3(const int* __restrict__ deg, const int* __restrict__ bsum,
                        int* __restrict__ rowptr, int n){
  __shared__ int wtot[4];
  int tid = threadIdx.x, lane = tid & 63, wid = tid >> 6;
  int base = blockIdx.x * SCHUNK + tid * 8;
  int l[8];
  int acc = 0;
  #pragma unroll
  for (int j = 0; j < 8; ++j){
    int i = base + j;
    acc += (i < n) ? deg[i] : 0;
    l[j] = acc;
  }
  int v = acc;
  #pragma unroll
  for (int off = 1; off < 64; off <<= 1){
    int u = __shfl_up(v, off);
    if (lane >= off) v += u;
  }
  if (lane == 63) wtot[wid] = v;
  __syncthreads();
  int woff = 0;
  for (int w = 0; w < wid; ++w) woff += wtot[w];
  int boff = (blockIdx.x == 0) ? 0 : bsum[blockIdx.x - 1];
  int tpre = boff + woff + (v - acc);
  #pragma unroll
  for (int j = 0; j < 8; ++j){
    int i = base + j;
    if (i < n) rowptr[i + 1] = tpre + l[j];
  }
  if (blockIdx.x == 0 && tid == 0) rowptr[0] = 0;
}

__global__ void k_scatter(const int* __restrict__ row, const int* __restrict__ col,
                          const int* __restrict__ rowptr, const int* __restrict__ rank,
                          int* __restrict__ cols_s, int E){
  int i = blockIdx.x * blockDim.x + threadIdx.x;
  if (i < E){
    cols_s[rowptr[row[i]] + rank[i]] = col[i];
  }
}

// ---------------- neighbor mean (r11 form) ----------------
__global__ void k_nmean(const float* __restrict__ x, const int* __restrict__ rowptr,
                        const int* __restrict__ cols, float* __restrict__ nmean, int n){
  __shared__ int s_cv[4][64];
  int wid = threadIdx.x >> 6;
  int node = blockIdx.x * 4 + wid;
  if (node >= n) return;
  int lane = threadIdx.x & 63;
  int s = rowptr[node], e = rowptr[node + 1];
  float acc = 0.f;
  for (int j0 = s; j0 < e; j0 += 64){
    int len = min(64, e - j0);
    int cv = (lane < len) ? cols[j0 + lane] : 0;
    s_cv[wid][lane] = cv;
    int k = 0;
    for (; k + 8 <= len; k += 8){
      float p[8];
      #pragma unroll
      for (int u = 0; u < 8; ++u){
        int c = s_cv[wid][k + u];
        p[u] = (lane < DIN) ? x[c * DIN + lane] : 0.f;
      }
      #pragma unroll
      for (int u = 0; u < 8; ++u) acc += p[u];
    }
    for (; k < len; ++k){
      int c = s_cv[wid][k];
      if (lane < DIN) acc += x[c * DIN + lane];
    }
  }
  if (lane < DIN){
    float d = (float)(e - s);
    nmean[node * DIN + lane] = acc / (d + 1e-8f);
  }
}

// ---------------- input projection (bf16 out) + fused layer-0 sh scores ----------------
__global__ void k_h_in(const float* __restrict__ x, const float* __restrict__ nmean,
                       const float* __restrict__ Win, const float* __restrict__ bin,
                       const float* __restrict__ Wagg, const float* __restrict__ bagg,
                       const float* __restrict__ asrc, const float* __restrict__ adst,
                       float* __restrict__ ssrc, float* __restrict__ sdst,
                       ushort_t* __restrict__ out, int n){
  int wid = threadIdx.x >> 6;
  int node = blockIdx.x * 4 + wid;
  if (node >= n) return;
  int lane = threadIdx.x & 63;
  float xv = 0.f;
  if (lane < DIN) xv = x[node * DIN + lane];
  else if (lane < 2 * DIN) xv = nmean[node * DIN + (lane - DIN)];
  float acc0 = bin[lane]      + bagg[lane];
  float acc1 = bin[64 + lane] + bagg[64 + lane];
  #pragma unroll
  for (int d = 0; d < DIN; ++d){
    float xd = __shfl(xv, d);
    float nd = __shfl(xv, DIN + d);
    acc0 += xd * Win[d * HID + lane]       + nd * Wagg[d * HID + lane];
    acc1 += xd * Win[d * HID + 64 + lane]  + nd * Wagg[d * HID + 64 + lane];
  }
  out[node * HID + lane]      = f2bf(acc0);
  out[node * HID + 64 + lane] = f2bf(acc1);
  float ps = acc0 * asrc[lane] + acc1 * asrc[64 + lane];
  float pd = acc0 * adst[lane] + acc1 * adst[64 + lane];
  ps = wred_sum(ps);
  pd = wred_sum(pd);
  if (lane == 0){ ssrc[node] = ps; sdst[node] = pd; }
}

// ---------------- weight prep: f32 [d][c] -> bf16 [c][d] ----------------
__global__ void k_wt_sh(const float* __restrict__ W, ushort_t* __restrict__ Wt){
  int i = blockIdx.x * 256 + threadIdx.x;
  int c = i >> 7, d = i & 127;
  Wt[c * HID + d] = f2bf(W[d * HID + c]);
}
__global__ void k_wt_mh(const float* __restrict__ mhWv, ushort_t* __restrict__ Wt){
  int i = blockIdx.x * 256 + threadIdx.x;
  int c = i >> 7, d = i & 127;
  Wt[c * HID + d] = f2bf(mhWv[((c >> 5) * HID + d) * 32 + (c & 31)]);
}

// ---------------- MFMA GEMM (bf16 A, bf16 out) ----------------
__global__ void k_gemm_mfma(const ushort_t* __restrict__ A, const ushort_t* __restrict__ Bt,
                            const float* __restrict__ bias, ushort_t* __restrict__ dstb,
                            int n){
  int wv = threadIdx.x >> 6, lane = threadIdx.x & 63;
  int r0 = blockIdx.x * 64 + wv * 16;
  int lr = lane & 15, lk = lane >> 4;
  int arow = r0 + lr; if (arow >= n) arow = n - 1;
  const ushort_t* Ap = A + (size_t)arow * HID + lk * 8;
  bf16x8 a[4];
  #pragma unroll
  for (int kb = 0; kb < 4; ++kb) a[kb] = *(const bf16x8*)(Ap + kb * 32);
  f32x4 acc[8];
  #pragma unroll
  for (int t = 0; t < 8; ++t) acc[t] = (f32x4){0.f, 0.f, 0.f, 0.f};
  #pragma unroll
  for (int t = 0; t < 8; ++t){
    const ushort_t* Bp = Bt + (size_t)(t * 16 + lr) * HID + lk * 8;
    #pragma unroll
    for (int kb = 0; kb < 4; ++kb){
      bf16x8 b = *(const bf16x8*)(Bp + kb * 32);
      acc[t] = __builtin_amdgcn_mfma_f32_16x16x32_bf16(a[kb], b, acc[t], 0, 0, 0);
    }
  }
  #pragma unroll
  for (int t = 0; t < 8; ++t){
    int col = t * 16 + lr;
    float bs = bias[col];
    #pragma unroll
    for (int j = 0; j < 4; ++j){
      int rr = r0 + lk * 4 + j;
      if (rr < n) dstb[(size_t)rr * HID + col] = f2bf(acc[t][j] + bs);
    }
  }
}

// ---------------- final GEMM + fused output head ----------------
__global__ void k_gemm_out(const ushort_t* __restrict__ A, const ushort_t* __restrict__ Bt,
                           const float* __restrict__ bias, const float* __restrict__ Wo2,
                           const float* __restrict__ bo2, const float* __restrict__ x,
                           float* __restrict__ out, int n){
  int wv = threadIdx.x >> 6, lane = threadIdx.x & 63;
  int r0 = blockIdx.x * 64 + wv * 16;
  int lr = lane & 15, lk = lane >> 4;
  int arow = r0 + lr; if (arow >= n) arow = n - 1;
  const ushort_t* Ap = A + (size_t)arow * HID + lk * 8;
  bf16x8 a[4];
  #pragma unroll
  for (int kb = 0; kb < 4; ++kb) a[kb] = *(const bf16x8*)(Ap + kb * 32);
  f32x4 acc[8];
  #pragma unroll
  for (int t = 0; t < 8; ++t) acc[t] = (f32x4){0.f, 0.f, 0.f, 0.f};
  #pragma unroll
  for (int t = 0; t < 8; ++t){
    const ushort_t* Bp = Bt + (size_t)(t * 16 + lr) * HID + lk * 8;
    #pragma unroll
    for (int kb = 0; kb < 4; ++kb){
      bf16x8 b = *(const bf16x8*)(Bp + kb * 32);
      acc[t] = __builtin_amdgcn_mfma_f32_16x16x32_bf16(a[kb], b, acc[t], 0, 0, 0);
    }
  }
  #pragma unroll
  for (int j = 0; j < 4; ++j){
    float p0 = 0.f, p1 = 0.f, p2 = 0.f;
    #pragma unroll
    for (int t = 0; t < 8; ++t){
      int col = t * 16 + lr;
      float v = leaky(acc[t][j] + bias[col]);
      p0 += v * Wo2[col * 3 + 0];
      p1 += v * Wo2[col * 3 + 1];
      p2 += v * Wo2[col * 3 + 2];
    }
    #pragma unroll
    for (int off = 1; off < 16; off <<= 1){
      p0 += __shfl_xor(p0, off);
      p1 += __shfl_xor(p1, off);
      p2 += __shfl_xor(p2, off);
    }
    int rr = r0 + lk * 4 + j;
    if (lr == 0 && rr < n){
      out[rr * 3 + 0] = x[rr * DIN + 15] + p0 + bo2[0];
      out[rr * 3 + 1] = x[rr * DIN + 16] + p1 + bo2[1];
      out[rr * 3 + 2] = x[rr * DIN + 17] + p2 + bo2[2];
    }
  }
}

// ---------------- single-head agg: async global_load_lds staged, 8 nodes/block ----------------
__global__ void k_agg_sh(const int* __restrict__ rowptr, const int* __restrict__ cols,
                         const float* __restrict__ ssrc, const float* __restrict__ sdst,
                         const ushort_t* __restrict__ hv, const ushort_t* __restrict__ resid,
                         const float* __restrict__ bng, const float* __restrict__ bnb,
                         const float* __restrict__ bnm, const float* __restrict__ bnv,
                         const float* __restrict__ masrc, const float* __restrict__ madst,
                         float* __restrict__ ossrc, float* __restrict__ osdst,
                         ushort_t* __restrict__ out, int n){
  __shared__ unsigned stage32[ET * 64];   // 64 KB: ET rows x 128 bf16
  __shared__ int   s_cv[ET];
  __shared__ float s_exf[ET];
  __shared__ int   s_rp[NB + 1];
  __shared__ float s_sq[NB];
  int node0 = blockIdx.x * NB;
  int tid = threadIdx.x, w = tid >> 6, lane = tid & 63;
  if (tid <= NB){
    int nd = min(node0 + tid, n);
    s_rp[tid] = rowptr[nd];
    if (tid < NB && node0 + tid < n) s_sq[tid] = ssrc[node0 + tid];
  }
  __syncthreads();
  int base = s_rp[0], end = s_rp[NB];
  float a0[2] = {0.f, 0.f}, a1[2] = {0.f, 0.f}, sm[2] = {0.f, 0.f};
  for (int tbase = base; tbase < end; tbase += ET){
    int cnt = min(ET, end - tbase);
    int cv = 0; float kd = 0.f;
    if (tid < cnt){
      cv = cols[tbase + tid];
      s_cv[tid] = cv;
      kd = sdst[cv];
    }
    __syncthreads();
    // async stage: wave w fires slots [w*64, w*64+64)
    for (int q = 0; q < 64; ++q){
      int sl = (w << 6) + q;
      if (sl < cnt){
        int c = s_cv[sl];
        gload_lds4(hv + (size_t)c * HID + (lane << 1), &stage32[sl * 64]);
      }
    }
    // per-edge alpha (overlaps with staging)
    if (tid < cnt){
      int gslot = tbase + tid;
      int ndl = 0;
      while (gslot >= s_rp[ndl + 1]) ++ndl;
      s_exf[tid] = __expf(leaky(s_sq[ndl] + kd));
    }
    __syncthreads();   // drains vmcnt: staged rows + alphas visible
    // consume: wave w owns local nodes 2w, 2w+1
    #pragma unroll
    for (int u = 0; u < 2; ++u){
      int ndl = (w << 1) + u;
      int lo = max(s_rp[ndl] - tbase, 0);
      int hi = min(s_rp[ndl + 1] - tbase, cnt);
      for (int k = lo; k < hi; ++k){
        float l = s_exf[k];
        unsigned p = stage32[k * 64 + lane];
        a0[u] += l * bf_lo(p);
        a1[u] += l * bf_hi(p);
        sm[u] += l;
      }
    }
    __syncthreads();
  }
  // epilogue
  #pragma unroll
  for (int u = 0; u < 2; ++u){
    int ndl = (w << 1) + u;
    int node = node0 + ndl;
    if (node >= n) continue;
    float inv = 1.f / (sm[u] + 1e-16f);
    float A0 = a0[u] * inv, A1 = a1[u] * inv;
    int d0 = 2 * lane, d1 = d0 + 1;
    float v0 = (A0 - bnm[d0]) * rsqrtf(bnv[d0] + BN_EPS) * bng[d0] + bnb[d0];
    float v1 = (A1 - bnm[d1]) * rsqrtf(bnv[d1] + BN_EPS) * bng[d1] + bnb[d1];
    if (resid){
      unsigned rv = *(const unsigned*)&resid[node * HID + d0];
      v0 += bf_lo(rv); v1 += bf_hi(rv);
    }
    float o0 = leaky(v0), o1 = leaky(v1);
    *(unsigned*)&out[node * HID + d0] = packbf(o0, o1);
    if (ossrc){
      #pragma unroll
      for (int h = 0; h < 4; ++h){
        float ps = o0 * masrc[h * HID + d0] + o1 * masrc[h * HID + d1];
        float pd = o0 * madst[h * HID + d0] + o1 * madst[h * HID + d1];
        ps = wred_sum(ps);
        pd = wred_sum(pd);
        if (lane == 0){ ossrc[node * 4 + h] = ps; osdst[node * 4 + h] = pd; }
      }
    }
  }
}

// ---------------- multi-head agg: async staged, 8 nodes/block ----------------
__global__ void k_agg_mh(const int* __restrict__ rowptr, const int* __restrict__ cols,
                         const float* __restrict__ ssrc, const float* __restrict__ sdst,
                         const ushort_t* __restrict__ hv,
                         const float* __restrict__ bng, const float* __restrict__ bnb,
                         const float* __restrict__ bnm, const float* __restrict__ bnv,
                         const float* __restrict__ sasrc, const float* __restrict__ sadst,
                         float* __restrict__ ossrc, float* __restrict__ osdst,
                         ushort_t* __restrict__ out, int n){
  __shared__ unsigned stage32[ET * 64];
  __shared__ int    s_cv[ET];
  __shared__ float4 s_ex4[ET];
  __shared__ int    s_rp[NB + 1];
  __shared__ float4 s_sq[NB];
  int node0 = blockIdx.x * NB;
  int tid = threadIdx.x, w = tid >> 6, lane = tid & 63;
  int hd = lane >> 4;   // head of dims (2*lane, 2*lane+1)
  if (tid <= NB){
    int nd = min(node0 + tid, n);
    s_rp[tid] = rowptr[nd];
    if (tid < NB && node0 + tid < n) s_sq[tid] = *(const float4*)&ssrc[(node0 + tid) * 4];
  }
  __syncthreads();
  int base = s_rp[0], end = s_rp[NB];
  float a0[2] = {0.f, 0.f}, a1[2] = {0.f, 0.f}, sm[2] = {0.f, 0.f};
  const float* exw = &s_ex4[0].x;
  for (int tbase = base; tbase < end; tbase += ET){
    int cnt = min(ET, end - tbase);
    int cv = 0; float4 kd = make_float4(0.f, 0.f, 0.f, 0.f);
    if (tid < cnt){
      cv = cols[tbase + tid];
      s_cv[tid] = cv;
      kd = *(const float4*)&sdst[cv * 4];
    }
    __syncthreads();
    for (int q = 0; q < 64; ++q){
      int sl = (w << 6) + q;
      if (sl < cnt){
        int c = s_cv[sl];
        gload_lds4(hv + (size_t)c * HID + (lane << 1), &stage32[sl * 64]);
      }
    }
    if (tid < cnt){
      int gslot = tbase + tid;
      int ndl = 0;
      while (gslot >= s_rp[ndl + 1]) ++ndl;
      float4 sq = s_sq[ndl];
      s_ex4[tid] = make_float4(__expf(leaky(sq.x + kd.x)), __expf(leaky(sq.y + kd.y)),
                               __expf(leaky(sq.z + kd.z)), __expf(leaky(sq.w + kd.w)));
    }
    __syncthreads();
    #pragma unroll
    for (int u = 0; u < 2; ++u){
      int ndl = (w << 1) + u;
      int lo = max(s_rp[ndl] - tbase, 0);
      int hi = min(s_rp[ndl + 1] - tbase, cnt);
      for (int k = lo; k < hi; ++k){
        float l = exw[k * 4 + hd];
        unsigned p = stage32[k * 64 + lane];
        a0[u] += l * bf_lo(p);
        a1[u] += l * bf_hi(p);
        sm[u] += l;
      }
    }
    __syncthreads();
  }
  #pragma unroll
  for (int u = 0; u < 2; ++u){
    int ndl = (w << 1) + u;
    int node = node0 + ndl;
    if (node >= n) continue;
    float ih = 1.f / (sm[u] + 1e-16f);
    float A0 = a0[u] * ih, A1 = a1[u] * ih;
    int d0 = 2 * lane, d1 = d0 + 1;
    float v0 = (A0 - bnm[d0]) * rsqrtf(bnv[d0] + BN_EPS) * bng[d0] + bnb[d0];
    float v1 = (A1 - bnm[d1]) * rsqrtf(bnv[d1] + BN_EPS) * bng[d1] + bnb[d1];
    float o0 = leaky(v0), o1 = leaky(v1);
    *(unsigned*)&out[node * HID + d0] = packbf(o0, o1);
    float ps = o0 * sasrc[d0] + o1 * sasrc[d1];
    float pd = o0 * sadst[d0] + o1 * sadst[d1];
    ps = wred_sum(ps);
    pd = wred_sum(pd);
    if (lane == 0){ ossrc[node] = ps; osdst[node] = pd; }
  }
}

extern "C" void kernel_launch(void* const* d_in, const int* in_sizes, int n_in,
                              void* d_out, int out_size, void* d_ws, size_t ws_size,
                              hipStream_t stream){
  const float* x       = (const float*)d_in[0];
  const int*   ei      = (const int*)  d_in[1];
  const float* W_in    = (const float*)d_in[2];
  const float* b_in    = (const float*)d_in[3];
  const float* W_agg   = (const float*)d_in[4];
  const float* b_agg   = (const float*)d_in[5];
  const float* sh_Wv   = (const float*)d_in[6];
  const float* sh_b    = (const float*)d_in[7];
  const float* sh_asrc = (const float*)d_in[8];
  const float* sh_adst = (const float*)d_in[9];
  const float* mh_Wv   = (const float*)d_in[10];
  const float* mh_b    = (const float*)d_in[11];
  const float* mh_asrc = (const float*)d_in[12];
  const float* mh_adst = (const float*)d_in[13];
  const float* bn_g    = (const float*)d_in[14];
  const float* bn_bt   = (const float*)d_in[15];
  const float* bn_m    = (const float*)d_in[16];
  const float* bn_v    = (const float*)d_in[17];
  const float* W_o1    = (const float*)d_in[18];
  const float* b_o1    = (const float*)d_in[19];
  const float* W_o2    = (const float*)d_in[20];
  const float* b_o2    = (const float*)d_in[21];
  float* out = (float*)d_out;

  const int N = in_sizes[0] / DIN;
  const int E = in_sizes[1] / 2;
  const int* row = ei;
  const int* col = ei + E;

  char* w = (char*)d_ws;
  size_t off = 0;
  auto alloc = [&](size_t bytes) -> void* {
    void* p = w + off;
    off = (off + bytes + 255) & ~(size_t)255;
    return p;
  };
  int*      tmp    = (int*)     alloc((size_t)N * 4);
  int*      rowptr = (int*)     alloc((size_t)(N + 1) * 4);
  int*      cols_s = (int*)     alloc((size_t)E * 4);
  int*      rank   = (int*)     alloc((size_t)E * 4);
  int*      bsum   = (int*)     alloc((size_t)1024 * 4);
  float*    nmean  = (float*)   alloc((size_t)N * DIN * 4);
  float*    ssrcA  = (float*)   alloc((size_t)N * 4);
  float*    sdstA  = (float*)   alloc((size_t)N * 4);
  float*    ssrcB  = (float*)   alloc((size_t)N * 4 * 4);
  float*    sdstB  = (float*)   alloc((size_t)N * 4 * 4);
  ushort_t* wt0    = (ushort_t*)alloc((size_t)HID * HID * 2);
  ushort_t* wt1    = (ushort_t*)alloc((size_t)HID * HID * 2);
  ushort_t* wt2    = (ushort_t*)alloc((size_t)HID * HID * 2);
  ushort_t* wt3    = (ushort_t*)alloc((size_t)HID * HID * 2);
  ushort_t* b0     = (ushort_t*)alloc((size_t)N * HID * 2);
  ushort_t* b1     = (ushort_t*)alloc((size_t)N * HID * 2);
  ushort_t* hvb    = (ushort_t*)alloc((size_t)N * HID * 2);

  const int eb = (E + 255) / 256;
  const int nb4 = (N + 3) / 4;
  const int nb8 = (N + NB - 1) / NB;
  const int gb = (N + 63) / 64;
  const int nsb = (N + SCHUNK - 1) / SCHUNK;

  // CSR build (one atomic pass)
  hipMemsetAsync(tmp, 0, (size_t)N * 4, stream);
  k_deg_rank<<<eb, 256, 0, stream>>>(row, tmp, rank, E);
  k_scan1<<<nsb, 256, 0, stream>>>(tmp, bsum, N);
  k_scan2<<<1, 64, 0, stream>>>(bsum, nsb);
  k_scan3<<<nsb, 256, 0, stream>>>(tmp, bsum, rowptr, N);
  k_scatter<<<eb, 256, 0, stream>>>(row, col, rowptr, rank, cols_s, E);

  // weight prep (bf16, transposed)
  k_wt_sh<<<64, 256, 0, stream>>>(sh_Wv, wt0);
  k_wt_mh<<<64, 256, 0, stream>>>(mh_Wv, wt1);
  k_wt_sh<<<64, 256, 0, stream>>>(sh_Wv + HID * HID, wt2);
  k_wt_sh<<<64, 256, 0, stream>>>(W_o1, wt3);

  // neighbor mean + input projection (+layer0 sh scores) -> b0 (bf16)
  k_nmean<<<nb4, 256, 0, stream>>>(x, rowptr, cols_s, nmean, N);
  k_h_in<<<nb4, 256, 0, stream>>>(x, nmean, W_in, b_in, W_agg, b_agg,
                                  sh_asrc, sh_adst, ssrcA, sdstA, b0, N);

  // layer 0: single-head, residual b0, bn[0] -> b1 (+mh scores)
  k_gemm_mfma<<<gb, 256, 0, stream>>>(b0, wt0, sh_b, hvb, N);
  k_agg_sh<<<nb8, 256, 0, stream>>>(rowptr, cols_s, ssrcA, sdstA, hvb, b0,
                                    bn_g, bn_bt, bn_m, bn_v,
                                    mh_asrc, mh_adst, ssrcB, sdstB, b1, N);

  // layer 1: multi-head, bn[1], no residual -> b0 (+layer2 sh scores)
  k_gemm_mfma<<<gb, 256, 0, stream>>>(b1, wt1, mh_b, hvb, N);
  k_agg_mh<<<nb8, 256, 0, stream>>>(rowptr, cols_s, ssrcB, sdstB, hvb,
                                    bn_g + HID, bn_bt + HID, bn_m + HID, bn_v + HID,
                                    sh_asrc + HID, sh_adst + HID, ssrcA, sdstA, b0, N);

  // layer 2: single-head, residual b0, bn[2] -> b1
  k_gemm_mfma<<<gb, 256, 0, stream>>>(b0, wt2, sh_b + HID, hvb, N);
  k_agg_sh<<<nb8, 256, 0, stream>>>(rowptr, cols_s, ssrcA, sdstA, hvb, b0,
                                    bn_g + 2 * HID, bn_bt + 2 * HID, bn_m + 2 * HID, bn_v + 2 * HID,
                                    nullptr, nullptr, nullptr, nullptr, b1, N);

  // output head fused into final GEMM
  k_gemm_out<<<gb, 256, 0, stream>>>(b1, wt3, b_o1, W_o2, b_o2, x, out, N);
}

// Round 14
// 351.246 us; speedup vs baseline: 1.7311x; 1.7311x over previous
//
#include <hip/hip_runtime.h>
#include <math.h>

#define DIN 18
#define HID 128
#define NEGS 0.2f
#define BN_EPS 1e-5f
#define SCHUNK 2048

typedef unsigned short ushort_t;
typedef __attribute__((ext_vector_type(8))) short bf16x8;
typedef __attribute__((ext_vector_type(4))) float f32x4;

__device__ __forceinline__ float leaky(float x){ return x >= 0.f ? x : NEGS * x; }

__device__ __forceinline__ float wred_sum(float v){
  #pragma unroll
  for (int off = 32; off; off >>= 1) v += __shfl_xor(v, off);
  return v;
}

__device__ __forceinline__ ushort_t f2bf(float f){
  union { float f; unsigned u; } v; v.f = f;
  unsigned r = v.u + 0x7FFFu + ((v.u >> 16) & 1u);
  return (ushort_t)(r >> 16);
}
__device__ __forceinline__ float bf_lo(unsigned p){ return __uint_as_float(p << 16); }
__device__ __forceinline__ float bf_hi(unsigned p){ return __uint_as_float(p & 0xFFFF0000u); }
__device__ __forceinline__ unsigned packbf(float a, float b){
  return (unsigned)f2bf(a) | ((unsigned)f2bf(b) << 16);
}

__device__ __forceinline__ float sel4(float v0, float v1, float v2, float v3, int hd){
  float a = (hd & 1) ? v1 : v0;
  float b = (hd & 1) ? v3 : v2;
  return (hd & 2) ? b : a;
}

// ---------------- CSR build: single atomic pass ----------------
__global__ void k_deg_rank(const int* __restrict__ row, int* __restrict__ deg,
                           int* __restrict__ rank, int E){
  int i = blockIdx.x * blockDim.x + threadIdx.x;
  if (i < E) rank[i] = atomicAdd(&deg[row[i]], 1);
}

__global__ void k_scan1(const int* __restrict__ deg, int* __restrict__ bsum, int n){
  __shared__ int wtot[4];
  int tid = threadIdx.x, lane = tid & 63, wid = tid >> 6;
  int base = blockIdx.x * SCHUNK + tid * 8;
  int acc = 0;
  #pragma unroll
  for (int j = 0; j < 8; ++j){
    int i = base + j;
    if (i < n) acc += deg[i];
  }
  #pragma unroll
  for (int off = 32; off; off >>= 1) acc += __shfl_xor(acc, off);
  if (lane == 0) wtot[wid] = acc;
  __syncthreads();
  if (tid == 0) bsum[blockIdx.x] = wtot[0] + wtot[1] + wtot[2] + wtot[3];
}

__global__ void k_scan2(int* __restrict__ bsum, int nb){
  int lane = threadIdx.x;
  int carry = 0;
  for (int base = 0; base < nb; base += 64){
    int i = base + lane;
    int v = (i < nb) ? bsum[i] : 0;
    #pragma unroll
    for (int off = 1; off < 64; off <<= 1){
      int u = __shfl_up(v, off);
      if (lane >= off) v += u;
    }
    if (i < nb) bsum[i] = v + carry;
    carry += __shfl(v, 63);
  }
}

__global__ void k_scan3(const int* __restrict__ deg, const int* __restrict__ bsum,
                        int* __restrict__ rowptr, int n){
  __shared__ int wtot[4];
  int tid = threadIdx.x, lane = tid & 63, wid = tid >> 6;
  int base = blockIdx.x * SCHUNK + tid * 8;
  int l[8];
  int acc = 0;
  #pragma unroll
  for (int j = 0; j < 8; ++j){
    int i = base + j;
    acc += (i < n) ? deg[i] : 0;
    l[j] = acc;
  }
  int v = acc;
  #pragma unroll
  for (int off = 1; off < 64; off <<= 1){
    int u = __shfl_up(v, off);
    if (lane >= off) v += u;
  }
  if (lane == 63) wtot[wid] = v;
  __syncthreads();
  int woff = 0;
  for (int w = 0; w < wid; ++w) woff += wtot[w];
  int boff = (blockIdx.x == 0) ? 0 : bsum[blockIdx.x - 1];
  int tpre = boff + woff + (v - acc);
  #pragma unroll
  for (int j = 0; j < 8; ++j){
    int i = base + j;
    if (i < n) rowptr[i + 1] = tpre + l[j];
  }
  if (blockIdx.x == 0 && tid == 0) rowptr[0] = 0;
}

__global__ void k_scatter(const int* __restrict__ row, const int* __restrict__ col,
                          const int* __restrict__ rowptr, const int* __restrict__ rank,
                          int* __restrict__ cols_s, int E){
  int i = blockIdx.x * blockDim.x + threadIdx.x;
  if (i < E){
    cols_s[rowptr[row[i]] + rank[i]] = col[i];
  }
}

// ---------------- fused weight prep: all 4 matrices, f32 -> bf16 transposed ----------------
__global__ void k_wtprep(const float* __restrict__ sh_Wv, const float* __restrict__ mhWv,
                         const float* __restrict__ W_o1,
                         ushort_t* __restrict__ wt0, ushort_t* __restrict__ wt1,
                         ushort_t* __restrict__ wt2, ushort_t* __restrict__ wt3){
  int b = blockIdx.x;
  int which = b >> 6;
  int i = (b & 63) * 256 + threadIdx.x;
  int c = i >> 7, d = i & 127;
  if (which == 0)      wt0[c * HID + d] = f2bf(sh_Wv[d * HID + c]);
  else if (which == 1) wt1[c * HID + d] = f2bf(mhWv[((c >> 5) * HID + d) * 32 + (c & 31)]);
  else if (which == 2) wt2[c * HID + d] = f2bf(sh_Wv[HID * HID + d * HID + c]);
  else                 wt3[c * HID + d] = f2bf(W_o1[d * HID + c]);
}

// ---------------- fused neighbor-mean + input projection + layer-0 sh scores ----------------
__global__ void k_nmean_hin(const float* __restrict__ x, const int* __restrict__ rowptr,
                            const int* __restrict__ cols,
                            const float* __restrict__ Win, const float* __restrict__ bin,
                            const float* __restrict__ Wagg, const float* __restrict__ bagg,
                            const float* __restrict__ asrc, const float* __restrict__ adst,
                            float* __restrict__ ssrc, float* __restrict__ sdst,
                            ushort_t* __restrict__ out, int n){
  __shared__ int s_cv[4][64];
  int wid = threadIdx.x >> 6;
  int node = blockIdx.x * 4 + wid;
  if (node >= n) return;
  int lane = threadIdx.x & 63;
  int s = rowptr[node], e = rowptr[node + 1];
  // phase 1: neighbor mean (lanes 0..17 active on gather)
  float acc = 0.f;
  for (int j0 = s; j0 < e; j0 += 64){
    int len = min(64, e - j0);
    int cv = (lane < len) ? cols[j0 + lane] : 0;
    s_cv[wid][lane] = cv;
    int k = 0;
    for (; k + 8 <= len; k += 8){
      float p[8];
      #pragma unroll
      for (int u = 0; u < 8; ++u){
        int c = s_cv[wid][k + u];
        p[u] = (lane < DIN) ? x[c * DIN + lane] : 0.f;
      }
      #pragma unroll
      for (int u = 0; u < 8; ++u) acc += p[u];
    }
    for (; k < len; ++k){
      int c = s_cv[wid][k];
      if (lane < DIN) acc += x[c * DIN + lane];
    }
  }
  float dg = (float)(e - s);
  float mean = (lane < DIN) ? acc / (dg + 1e-8f) : 0.f;
  // hand-off: lanes 0..17 hold x row, lanes 18..35 get mean dims via shfl
  float xv;
  if (lane < DIN) xv = x[node * DIN + lane];
  else            xv = __shfl(mean, lane - DIN);
  // phase 2: projection + scores
  float acc0 = bin[lane]      + bagg[lane];
  float acc1 = bin[64 + lane] + bagg[64 + lane];
  #pragma unroll
  for (int d = 0; d < DIN; ++d){
    float xd = __shfl(xv, d);
    float nd = __shfl(xv, DIN + d);
    acc0 += xd * Win[d * HID + lane]       + nd * Wagg[d * HID + lane];
    acc1 += xd * Win[d * HID + 64 + lane]  + nd * Wagg[d * HID + 64 + lane];
  }
  out[node * HID + lane]      = f2bf(acc0);
  out[node * HID + 64 + lane] = f2bf(acc1);
  float ps = acc0 * asrc[lane] + acc1 * asrc[64 + lane];
  float pd = acc0 * adst[lane] + acc1 * adst[64 + lane];
  ps = wred_sum(ps);
  pd = wred_sum(pd);
  if (lane == 0){ ssrc[node] = ps; sdst[node] = pd; }
}

// ---------------- MFMA GEMM (bf16 A, bf16 out) ----------------
__global__ void k_gemm_mfma(const ushort_t* __restrict__ A, const ushort_t* __restrict__ Bt,
                            const float* __restrict__ bias, ushort_t* __restrict__ dstb,
                            int n){
  int wv = threadIdx.x >> 6, lane = threadIdx.x & 63;
  int r0 = blockIdx.x * 64 + wv * 16;
  int lr = lane & 15, lk = lane >> 4;
  int arow = r0 + lr; if (arow >= n) arow = n - 1;
  const ushort_t* Ap = A + (size_t)arow * HID + lk * 8;
  bf16x8 a[4];
  #pragma unroll
  for (int kb = 0; kb < 4; ++kb) a[kb] = *(const bf16x8*)(Ap + kb * 32);
  f32x4 acc[8];
  #pragma unroll
  for (int t = 0; t < 8; ++t) acc[t] = (f32x4){0.f, 0.f, 0.f, 0.f};
  #pragma unroll
  for (int t = 0; t < 8; ++t){
    const ushort_t* Bp = Bt + (size_t)(t * 16 + lr) * HID + lk * 8;
    #pragma unroll
    for (int kb = 0; kb < 4; ++kb){
      bf16x8 b = *(const bf16x8*)(Bp + kb * 32);
      acc[t] = __builtin_amdgcn_mfma_f32_16x16x32_bf16(a[kb], b, acc[t], 0, 0, 0);
    }
  }
  #pragma unroll
  for (int t = 0; t < 8; ++t){
    int col = t * 16 + lr;
    float bs = bias[col];
    #pragma unroll
    for (int j = 0; j < 4; ++j){
      int rr = r0 + lk * 4 + j;
      if (rr < n) dstb[(size_t)rr * HID + col] = f2bf(acc[t][j] + bs);
    }
  }
}

// ---------------- final GEMM + fused output head ----------------
__global__ void k_gemm_out(const ushort_t* __restrict__ A, const ushort_t* __restrict__ Bt,
                           const float* __restrict__ bias, const float* __restrict__ Wo2,
                           const float* __restrict__ bo2, const float* __restrict__ x,
                           float* __restrict__ out, int n){
  int wv = threadIdx.x >> 6, lane = threadIdx.x & 63;
  int r0 = blockIdx.x * 64 + wv * 16;
  int lr = lane & 15, lk = lane >> 4;
  int arow = r0 + lr; if (arow >= n) arow = n - 1;
  const ushort_t* Ap = A + (size_t)arow * HID + lk * 8;
  bf16x8 a[4];
  #pragma unroll
  for (int kb = 0; kb < 4; ++kb) a[kb] = *(const bf16x8*)(Ap + kb * 32);
  f32x4 acc[8];
  #pragma unroll
  for (int t = 0; t < 8; ++t) acc[t] = (f32x4){0.f, 0.f, 0.f, 0.f};
  #pragma unroll
  for (int t = 0; t < 8; ++t){
    const ushort_t* Bp = Bt + (size_t)(t * 16 + lr) * HID + lk * 8;
    #pragma unroll
    for (int kb = 0; kb < 4; ++kb){
      bf16x8 b = *(const bf16x8*)(Bp + kb * 32);
      acc[t] = __builtin_amdgcn_mfma_f32_16x16x32_bf16(a[kb], b, acc[t], 0, 0, 0);
    }
  }
  #pragma unroll
  for (int j = 0; j < 4; ++j){
    float p0 = 0.f, p1 = 0.f, p2 = 0.f;
    #pragma unroll
    for (int t = 0; t < 8; ++t){
      int col = t * 16 + lr;
      float v = leaky(acc[t][j] + bias[col]);
      p0 += v * Wo2[col * 3 + 0];
      p1 += v * Wo2[col * 3 + 1];
      p2 += v * Wo2[col * 3 + 2];
    }
    #pragma unroll
    for (int off = 1; off < 16; off <<= 1){
      p0 += __shfl_xor(p0, off);
      p1 += __shfl_xor(p1, off);
      p2 += __shfl_xor(p2, off);
    }
    int rr = r0 + lk * 4 + j;
    if (lr == 0 && rr < n){
      out[rr * 3 + 0] = x[rr * DIN + 15] + p0 + bo2[0];
      out[rr * 3 + 1] = x[rr * DIN + 16] + p1 + bo2[1];
      out[rr * 3 + 2] = x[rr * DIN + 17] + p2 + bo2[2];
    }
  }
}

// ---------------- single-head aggregation (r11 form) + optional fused mh scores ----------------
__global__ void k_agg_sh(const int* __restrict__ rowptr, const int* __restrict__ cols,
                         const float* __restrict__ ssrc, const float* __restrict__ sdst,
                         const ushort_t* __restrict__ hv, const ushort_t* __restrict__ resid,
                         const float* __restrict__ bng, const float* __restrict__ bnb,
                         const float* __restrict__ bnm, const float* __restrict__ bnv,
                         const float* __restrict__ masrc, const float* __restrict__ madst,
                         float* __restrict__ ossrc, float* __restrict__ osdst,
                         ushort_t* __restrict__ out, int n){
  __shared__ int   s_cv[4][64];
  __shared__ float s_ex[4][64];
  int wid = threadIdx.x >> 6;
  int node = blockIdx.x * 4 + wid;
  if (node >= n) return;
  int lane = threadIdx.x & 63;
  const unsigned* hv32 = (const unsigned*)hv;
  int s = rowptr[node], e = rowptr[node + 1];
  float sq = ssrc[node];
  float ssum = 0.f, a0 = 0.f, a1 = 0.f;
  for (int j0 = s; j0 < e; j0 += 64){
    int len = min(64, e - j0);
    int cv = 0; float ex = 0.f;
    if (lane < len){
      cv = cols[j0 + lane];
      ex = __expf(leaky(sq + sdst[cv]));
    }
    ssum += ex;
    s_cv[wid][lane] = cv;
    s_ex[wid][lane] = ex;
    int k = 0;
    for (; k + 16 <= len; k += 16){
      unsigned p[16]; float l[16];
      #pragma unroll
      for (int u = 0; u < 16; ++u){
        int c = s_cv[wid][k + u];
        l[u] = s_ex[wid][k + u];
        p[u] = hv32[c * 64 + lane];
      }
      #pragma unroll
      for (int u = 0; u < 16; ++u){
        a0 += l[u] * bf_lo(p[u]); a1 += l[u] * bf_hi(p[u]);
      }
    }
    for (; k + 8 <= len; k += 8){
      unsigned p[8]; float l[8];
      #pragma unroll
      for (int u = 0; u < 8; ++u){
        int c = s_cv[wid][k + u];
        l[u] = s_ex[wid][k + u];
        p[u] = hv32[c * 64 + lane];
      }
      #pragma unroll
      for (int u = 0; u < 8; ++u){
        a0 += l[u] * bf_lo(p[u]); a1 += l[u] * bf_hi(p[u]);
      }
    }
    for (; k + 4 <= len; k += 4){
      unsigned p[4]; float l[4];
      #pragma unroll
      for (int u = 0; u < 4; ++u){
        int c = s_cv[wid][k + u];
        l[u] = s_ex[wid][k + u];
        p[u] = hv32[c * 64 + lane];
      }
      #pragma unroll
      for (int u = 0; u < 4; ++u){
        a0 += l[u] * bf_lo(p[u]); a1 += l[u] * bf_hi(p[u]);
      }
    }
    for (; k < len; ++k){
      int c = s_cv[wid][k];
      float l = s_ex[wid][k];
      unsigned p = hv32[c * 64 + lane];
      a0 += l * bf_lo(p); a1 += l * bf_hi(p);
    }
  }
  ssum = wred_sum(ssum);
  float inv = 1.f / (ssum + 1e-16f);
  a0 *= inv; a1 *= inv;
  int d0 = 2 * lane, d1 = 2 * lane + 1;
  float v0 = (a0 - bnm[d0]) * rsqrtf(bnv[d0] + BN_EPS) * bng[d0] + bnb[d0];
  float v1 = (a1 - bnm[d1]) * rsqrtf(bnv[d1] + BN_EPS) * bng[d1] + bnb[d1];
  if (resid){
    unsigned rv = *(const unsigned*)&resid[node * HID + d0];
    v0 += bf_lo(rv); v1 += bf_hi(rv);
  }
  float o0 = leaky(v0), o1 = leaky(v1);
  *(unsigned*)&out[node * HID + d0] = packbf(o0, o1);
  if (ossrc){
    #pragma unroll
    for (int h = 0; h < 4; ++h){
      float ps = o0 * masrc[h * HID + d0] + o1 * masrc[h * HID + d1];
      float pd = o0 * madst[h * HID + d0] + o1 * madst[h * HID + d1];
      ps = wred_sum(ps);
      pd = wred_sum(pd);
      if (lane == 0){ ossrc[node * 4 + h] = ps; osdst[node * 4 + h] = pd; }
    }
  }
}

// ---------------- multi-head aggregation (r11 form) + fused layer-2 sh scores ----------------
__global__ void k_agg_mh(const int* __restrict__ rowptr, const int* __restrict__ cols,
                         const float* __restrict__ ssrc, const float* __restrict__ sdst,
                         const ushort_t* __restrict__ hv,
                         const float* __restrict__ bng, const float* __restrict__ bnb,
                         const float* __restrict__ bnm, const float* __restrict__ bnv,
                         const float* __restrict__ sasrc, const float* __restrict__ sadst,
                         float* __restrict__ ossrc, float* __restrict__ osdst,
                         ushort_t* __restrict__ out, int n){
  __shared__ int    s_cv[4][64];
  __shared__ float4 s_ex[4][64];
  int wid = threadIdx.x >> 6;
  int node = blockIdx.x * 4 + wid;
  if (node >= n) return;
  int lane = threadIdx.x & 63;
  const unsigned* hv32 = (const unsigned*)hv;
  int s = rowptr[node], e = rowptr[node + 1];
  const float4 sq = *(const float4*)&ssrc[node * 4];
  int hd = lane >> 4;
  float s0 = 0.f, s1 = 0.f, s2 = 0.f, s3 = 0.f;
  float a0 = 0.f, a1 = 0.f;
  const float* exw = &s_ex[wid][0].x;
  for (int j0 = s; j0 < e; j0 += 64){
    int len = min(64, e - j0);
    int cv = 0;
    float e0 = 0.f, e1 = 0.f, e2 = 0.f, e3 = 0.f;
    if (lane < len){
      cv = cols[j0 + lane];
      float4 kd = *(const float4*)&sdst[cv * 4];
      e0 = __expf(leaky(sq.x + kd.x)); e1 = __expf(leaky(sq.y + kd.y));
      e2 = __expf(leaky(sq.z + kd.z)); e3 = __expf(leaky(sq.w + kd.w));
    }
    s0 += e0; s1 += e1; s2 += e2; s3 += e3;
    s_cv[wid][lane] = cv;
    s_ex[wid][lane] = make_float4(e0, e1, e2, e3);
    int k = 0;
    for (; k + 16 <= len; k += 16){
      unsigned p[16]; float l[16];
      #pragma unroll
      for (int u = 0; u < 16; ++u){
        int c = s_cv[wid][k + u];
        l[u] = exw[(k + u) * 4 + hd];
        p[u] = hv32[c * 64 + lane];
      }
      #pragma unroll
      for (int u = 0; u < 16; ++u){
        a0 += l[u] * bf_lo(p[u]); a1 += l[u] * bf_hi(p[u]);
      }
    }
    for (; k + 8 <= len; k += 8){
      unsigned p[8]; float l[8];
      #pragma unroll
      for (int u = 0; u < 8; ++u){
        int c = s_cv[wid][k + u];
        l[u] = exw[(k + u) * 4 + hd];
        p[u] = hv32[c * 64 + lane];
      }
      #pragma unroll
      for (int u = 0; u < 8; ++u){
        a0 += l[u] * bf_lo(p[u]); a1 += l[u] * bf_hi(p[u]);
      }
    }
    for (; k + 4 <= len; k += 4){
      unsigned p[4]; float l[4];
      #pragma unroll
      for (int u = 0; u < 4; ++u){
        int c = s_cv[wid][k + u];
        l[u] = exw[(k + u) * 4 + hd];
        p[u] = hv32[c * 64 + lane];
      }
      #pragma unroll
      for (int u = 0; u < 4; ++u){
        a0 += l[u] * bf_lo(p[u]); a1 += l[u] * bf_hi(p[u]);
      }
    }
    for (; k < len; ++k){
      int c = s_cv[wid][k];
      float l = exw[k * 4 + hd];
      unsigned p = hv32[c * 64 + lane];
      a0 += l * bf_lo(p); a1 += l * bf_hi(p);
    }
  }
  s0 = wred_sum(s0); s1 = wred_sum(s1);
  s2 = wred_sum(s2); s3 = wred_sum(s3);
  float i0 = 1.f / (s0 + 1e-16f), i1 = 1.f / (s1 + 1e-16f);
  float i2 = 1.f / (s2 + 1e-16f), i3 = 1.f / (s3 + 1e-16f);
  float ih = sel4(i0, i1, i2, i3, hd);
  a0 *= ih; a1 *= ih;
  int d0 = 2 * lane, d1 = 2 * lane + 1;
  float v0 = (a0 - bnm[d0]) * rsqrtf(bnv[d0] + BN_EPS) * bng[d0] + bnb[d0];
  float v1 = (a1 - bnm[d1]) * rsqrtf(bnv[d1] + BN_EPS) * bng[d1] + bnb[d1];
  float o0 = leaky(v0), o1 = leaky(v1);
  *(unsigned*)&out[node * HID + d0] = packbf(o0, o1);
  float ps = o0 * sasrc[d0] + o1 * sasrc[d1];
  float pd = o0 * sadst[d0] + o1 * sadst[d1];
  ps = wred_sum(ps);
  pd = wred_sum(pd);
  if (lane == 0){ ossrc[node] = ps; osdst[node] = pd; }
}

extern "C" void kernel_launch(void* const* d_in, const int* in_sizes, int n_in,
                              void* d_out, int out_size, void* d_ws, size_t ws_size,
                              hipStream_t stream){
  const float* x       = (const float*)d_in[0];
  const int*   ei      = (const int*)  d_in[1];
  const float* W_in    = (const float*)d_in[2];
  const float* b_in    = (const float*)d_in[3];
  const float* W_agg   = (const float*)d_in[4];
  const float* b_agg   = (const float*)d_in[5];
  const float* sh_Wv   = (const float*)d_in[6];
  const float* sh_b    = (const float*)d_in[7];
  const float* sh_asrc = (const float*)d_in[8];
  const float* sh_adst = (const float*)d_in[9];
  const float* mh_Wv   = (const float*)d_in[10];
  const float* mh_b    = (const float*)d_in[11];
  const float* mh_asrc = (const float*)d_in[12];
  const float* mh_adst = (const float*)d_in[13];
  const float* bn_g    = (const float*)d_in[14];
  const float* bn_bt   = (const float*)d_in[15];
  const float* bn_m    = (const float*)d_in[16];
  const float* bn_v    = (const float*)d_in[17];
  const float* W_o1    = (const float*)d_in[18];
  const float* b_o1    = (const float*)d_in[19];
  const float* W_o2    = (const float*)d_in[20];
  const float* b_o2    = (const float*)d_in[21];
  float* out = (float*)d_out;

  const int N = in_sizes[0] / DIN;
  const int E = in_sizes[1] / 2;
  const int* row = ei;
  const int* col = ei + E;

  char* w = (char*)d_ws;
  size_t off = 0;
  auto alloc = [&](size_t bytes) -> void* {
    void* p = w + off;
    off = (off + bytes + 255) & ~(size_t)255;
    return p;
  };
  int*      tmp    = (int*)     alloc((size_t)N * 4);
  int*      rowptr = (int*)     alloc((size_t)(N + 1) * 4);
  int*      cols_s = (int*)     alloc((size_t)E * 4);
  int*      rank   = (int*)     alloc((size_t)E * 4);
  int*      bsum   = (int*)     alloc((size_t)1024 * 4);
  float*    ssrcA  = (float*)   alloc((size_t)N * 4);
  float*    sdstA  = (float*)   alloc((size_t)N * 4);
  float*    ssrcB  = (float*)   alloc((size_t)N * 4 * 4);
  float*    sdstB  = (float*)   alloc((size_t)N * 4 * 4);
  ushort_t* wt0    = (ushort_t*)alloc((size_t)HID * HID * 2);
  ushort_t* wt1    = (ushort_t*)alloc((size_t)HID * HID * 2);
  ushort_t* wt2    = (ushort_t*)alloc((size_t)HID * HID * 2);
  ushort_t* wt3    = (ushort_t*)alloc((size_t)HID * HID * 2);
  ushort_t* b0     = (ushort_t*)alloc((size_t)N * HID * 2);
  ushort_t* b1     = (ushort_t*)alloc((size_t)N * HID * 2);
  ushort_t* hvb    = (ushort_t*)alloc((size_t)N * HID * 2);

  const int eb = (E + 255) / 256;
  const int nb4 = (N + 3) / 4;
  const int gb = (N + 63) / 64;
  const int nsb = (N + SCHUNK - 1) / SCHUNK;

  // CSR build (one atomic pass)
  hipMemsetAsync(tmp, 0, (size_t)N * 4, stream);
  k_deg_rank<<<eb, 256, 0, stream>>>(row, tmp, rank, E);
  k_scan1<<<nsb, 256, 0, stream>>>(tmp, bsum, N);
  k_scan2<<<1, 64, 0, stream>>>(bsum, nsb);
  k_scan3<<<nsb, 256, 0, stream>>>(tmp, bsum, rowptr, N);
  k_scatter<<<eb, 256, 0, stream>>>(row, col, rowptr, rank, cols_s, E);

  // fused weight prep (bf16, transposed)
  k_wtprep<<<256, 256, 0, stream>>>(sh_Wv, mh_Wv, W_o1, wt0, wt1, wt2, wt3);

  // fused nmean + input projection (+layer0 sh scores) -> b0 (bf16)
  k_nmean_hin<<<nb4, 256, 0, stream>>>(x, rowptr, cols_s, W_in, b_in, W_agg, b_agg,
                                       sh_asrc, sh_adst, ssrcA, sdstA, b0, N);

  // layer 0: single-head, residual b0, bn[0] -> b1 (+mh scores)
  k_gemm_mfma<<<gb, 256, 0, stream>>>(b0, wt0, sh_b, hvb, N);
  k_agg_sh<<<nb4, 256, 0, stream>>>(rowptr, cols_s, ssrcA, sdstA, hvb, b0,
                                    bn_g, bn_bt, bn_m, bn_v,
                                    mh_asrc, mh_adst, ssrcB, sdstB, b1, N);

  // layer 1: multi-head, bn[1], no residual -> b0 (+layer2 sh scores)
  k_gemm_mfma<<<gb, 256, 0, stream>>>(b1, wt1, mh_b, hvb, N);
  k_agg_mh<<<nb4, 256, 0, stream>>>(rowptr, cols_s, ssrcB, sdstB, hvb,
                                    bn_g + HID, bn_bt + HID, bn_m + HID, bn_v + HID,
                                    sh_asrc + HID, sh_adst + HID, ssrcA, sdstA, b0, N);

  // layer 2: single-head, residual b0, bn[2] -> b1
  k_gemm_mfma<<<gb, 256, 0, stream>>>(b0, wt2, sh_b + HID, hvb, N);
  k_agg_sh<<<nb4, 256, 0, stream>>>(rowptr, cols_s, ssrcA, sdstA, hvb, b0,
                                    bn_g + 2 * HID, bn_bt + 2 * HID, bn_m + 2 * HID, bn_v + 2 * HID,
                                    nullptr, nullptr, nullptr, nullptr, b1, N);

  // output head fused into final GEMM
  k_gemm_out<<<gb, 256, 0, stream>>>(b1, wt3, b_o1, W_o2, b_o2, x, out, N);
}

// Round 15
// 349.220 us; speedup vs baseline: 1.7411x; 1.0058x over previous
//
#include <hip/hip_runtime.h>
#include <math.h>

#define DIN 18
#define HID 128
#define NEGS 0.2f
#define BN_EPS 1e-5f
#define SCHUNK 2048
#define BSH 13          // bucket shift: 8192 nodes/bucket -> 2MB hv slice

typedef unsigned short ushort_t;
typedef __attribute__((ext_vector_type(8))) short bf16x8;
typedef __attribute__((ext_vector_type(4))) float f32x4;

__device__ __forceinline__ float leaky(float x){ return x >= 0.f ? x : NEGS * x; }

__device__ __forceinline__ float wred_sum(float v){
  #pragma unroll
  for (int off = 32; off; off >>= 1) v += __shfl_xor(v, off);
  return v;
}

__device__ __forceinline__ ushort_t f2bf(float f){
  union { float f; unsigned u; } v; v.f = f;
  unsigned r = v.u + 0x7FFFu + ((v.u >> 16) & 1u);
  return (ushort_t)(r >> 16);
}
__device__ __forceinline__ float bf_lo(unsigned p){ return __uint_as_float(p << 16); }
__device__ __forceinline__ float bf_hi(unsigned p){ return __uint_as_float(p & 0xFFFF0000u); }
__device__ __forceinline__ unsigned packbf(float a, float b){
  return (unsigned)f2bf(a) | ((unsigned)f2bf(b) << 16);
}

__device__ __forceinline__ float sel4(float v0, float v1, float v2, float v3, int hd){
  float a = (hd & 1) ? v1 : v0;
  float b = (hd & 1) ? v3 : v2;
  return (hd & 2) ? b : a;
}

// ---------------- bucketed CSR build: key = row*nbk + (col>>BSH) ----------------
__global__ void k_deg_rank(const int* __restrict__ row, const int* __restrict__ col,
                           int* __restrict__ deg, int* __restrict__ rank, int E, int nbk){
  int i = blockIdx.x * blockDim.x + threadIdx.x;
  if (i < E){
    int key = row[i] * nbk + (col[i] >> BSH);
    rank[i] = atomicAdd(&deg[key], 1);
  }
}

__global__ void k_scan1(const int* __restrict__ deg, int* __restrict__ bsum, int n){
  __shared__ int wtot[4];
  int tid = threadIdx.x, lane = tid & 63, wid = tid >> 6;
  int base = blockIdx.x * SCHUNK + tid * 8;
  int acc = 0;
  #pragma unroll
  for (int j = 0; j < 8; ++j){
    int i = base + j;
    if (i < n) acc += deg[i];
  }
  #pragma unroll
  for (int off = 32; off; off >>= 1) acc += __shfl_xor(acc, off);
  if (lane == 0) wtot[wid] = acc;
  __syncthreads();
  if (tid == 0) bsum[blockIdx.x] = wtot[0] + wtot[1] + wtot[2] + wtot[3];
}

__global__ void k_scan2(int* __restrict__ bsum, int nb){
  int lane = threadIdx.x;
  int carry = 0;
  for (int base = 0; base < nb; base += 64){
    int i = base + lane;
    int v = (i < nb) ? bsum[i] : 0;
    #pragma unroll
    for (int off = 1; off < 64; off <<= 1){
      int u = __shfl_up(v, off);
      if (lane >= off) v += u;
    }
    if (i < nb) bsum[i] = v + carry;
    carry += __shfl(v, 63);
  }
}

__global__ void k_scan3(const int* __restrict__ deg, const int* __restrict__ bsum,
                        int* __restrict__ rowptr, int n){
  __shared__ int wtot[4];
  int tid = threadIdx.x, lane = tid & 63, wid = tid >> 6;
  int base = blockIdx.x * SCHUNK + tid * 8;
  int l[8];
  int acc = 0;
  #pragma unroll
  for (int j = 0; j < 8; ++j){
    int i = base + j;
    acc += (i < n) ? deg[i] : 0;
    l[j] = acc;
  }
  int v = acc;
  #pragma unroll
  for (int off = 1; off < 64; off <<= 1){
    int u = __shfl_up(v, off);
    if (lane >= off) v += u;
  }
  if (lane == 63) wtot[wid] = v;
  __syncthreads();
  int woff = 0;
  for (int w = 0; w < wid; ++w) woff += wtot[w];
  int boff = (blockIdx.x == 0) ? 0 : bsum[blockIdx.x - 1];
  int tpre = boff + woff + (v - acc);
  #pragma unroll
  for (int j = 0; j < 8; ++j){
    int i = base + j;
    if (i < n) rowptr[i + 1] = tpre + l[j];
  }
  if (blockIdx.x == 0 && tid == 0) rowptr[0] = 0;
}

__global__ void k_scatter(const int* __restrict__ row, const int* __restrict__ col,
                          const int* __restrict__ rowptr, const int* __restrict__ rank,
                          int* __restrict__ cols_s, int E, int nbk){
  int i = blockIdx.x * blockDim.x + threadIdx.x;
  if (i < E){
    int c = col[i];
    int key = row[i] * nbk + (c >> BSH);
    cols_s[rowptr[key] + rank[i]] = c;
  }
}

// ---------------- fused weight prep ----------------
__global__ void k_wtprep(const float* __restrict__ sh_Wv, const float* __restrict__ mhWv,
                         const float* __restrict__ W_o1,
                         ushort_t* __restrict__ wt0, ushort_t* __restrict__ wt1,
                         ushort_t* __restrict__ wt2, ushort_t* __restrict__ wt3){
  int b = blockIdx.x;
  int which = b >> 6;
  int i = (b & 63) * 256 + threadIdx.x;
  int c = i >> 7, d = i & 127;
  if (which == 0)      wt0[c * HID + d] = f2bf(sh_Wv[d * HID + c]);
  else if (which == 1) wt1[c * HID + d] = f2bf(mhWv[((c >> 5) * HID + d) * 32 + (c & 31)]);
  else if (which == 2) wt2[c * HID + d] = f2bf(sh_Wv[HID * HID + d * HID + c]);
  else                 wt3[c * HID + d] = f2bf(W_o1[d * HID + c]);
}

// ---------------- fused neighbor-mean + input projection + layer-0 sh scores ----------------
__global__ void k_nmean_hin(const float* __restrict__ x, const int* __restrict__ rowptr,
                            const int* __restrict__ cols,
                            const float* __restrict__ Win, const float* __restrict__ bin,
                            const float* __restrict__ Wagg, const float* __restrict__ bagg,
                            const float* __restrict__ asrc, const float* __restrict__ adst,
                            float* __restrict__ ssrc, float* __restrict__ sdst,
                            ushort_t* __restrict__ out, int n, int nbk){
  __shared__ int s_cv[4][64];
  int wid = threadIdx.x >> 6;
  int node = blockIdx.x * 4 + wid;
  if (node >= n) return;
  int lane = threadIdx.x & 63;
  int s = rowptr[node * nbk], e = rowptr[(node + 1) * nbk];
  float acc = 0.f;
  for (int j0 = s; j0 < e; j0 += 64){
    int len = min(64, e - j0);
    int cv = (lane < len) ? cols[j0 + lane] : 0;
    s_cv[wid][lane] = cv;
    int k = 0;
    for (; k + 8 <= len; k += 8){
      float p[8];
      #pragma unroll
      for (int u = 0; u < 8; ++u){
        int c = s_cv[wid][k + u];
        p[u] = (lane < DIN) ? x[c * DIN + lane] : 0.f;
      }
      #pragma unroll
      for (int u = 0; u < 8; ++u) acc += p[u];
    }
    for (; k < len; ++k){
      int c = s_cv[wid][k];
      if (lane < DIN) acc += x[c * DIN + lane];
    }
  }
  float dg = (float)(e - s);
  float mean = (lane < DIN) ? acc / (dg + 1e-8f) : 0.f;
  float xv;
  if (lane < DIN) xv = x[node * DIN + lane];
  else            xv = __shfl(mean, lane - DIN);
  float acc0 = bin[lane]      + bagg[lane];
  float acc1 = bin[64 + lane] + bagg[64 + lane];
  #pragma unroll
  for (int d = 0; d < DIN; ++d){
    float xd = __shfl(xv, d);
    float nd = __shfl(xv, DIN + d);
    acc0 += xd * Win[d * HID + lane]       + nd * Wagg[d * HID + lane];
    acc1 += xd * Win[d * HID + 64 + lane]  + nd * Wagg[d * HID + 64 + lane];
  }
  out[node * HID + lane]      = f2bf(acc0);
  out[node * HID + 64 + lane] = f2bf(acc1);
  float ps = acc0 * asrc[lane] + acc1 * asrc[64 + lane];
  float pd = acc0 * adst[lane] + acc1 * adst[64 + lane];
  ps = wred_sum(ps);
  pd = wred_sum(pd);
  if (lane == 0){ ssrc[node] = ps; sdst[node] = pd; }
}

// ---------------- MFMA GEMM (bf16 A, bf16 out) ----------------
__global__ void k_gemm_mfma(const ushort_t* __restrict__ A, const ushort_t* __restrict__ Bt,
                            const float* __restrict__ bias, ushort_t* __restrict__ dstb,
                            int n){
  int wv = threadIdx.x >> 6, lane = threadIdx.x & 63;
  int r0 = blockIdx.x * 64 + wv * 16;
  int lr = lane & 15, lk = lane >> 4;
  int arow = r0 + lr; if (arow >= n) arow = n - 1;
  const ushort_t* Ap = A + (size_t)arow * HID + lk * 8;
  bf16x8 a[4];
  #pragma unroll
  for (int kb = 0; kb < 4; ++kb) a[kb] = *(const bf16x8*)(Ap + kb * 32);
  f32x4 acc[8];
  #pragma unroll
  for (int t = 0; t < 8; ++t) acc[t] = (f32x4){0.f, 0.f, 0.f, 0.f};
  #pragma unroll
  for (int t = 0; t < 8; ++t){
    const ushort_t* Bp = Bt + (size_t)(t * 16 + lr) * HID + lk * 8;
    #pragma unroll
    for (int kb = 0; kb < 4; ++kb){
      bf16x8 b = *(const bf16x8*)(Bp + kb * 32);
      acc[t] = __builtin_amdgcn_mfma_f32_16x16x32_bf16(a[kb], b, acc[t], 0, 0, 0);
    }
  }
  #pragma unroll
  for (int t = 0; t < 8; ++t){
    int col = t * 16 + lr;
    float bs = bias[col];
    #pragma unroll
    for (int j = 0; j < 4; ++j){
      int rr = r0 + lk * 4 + j;
      if (rr < n) dstb[(size_t)rr * HID + col] = f2bf(acc[t][j] + bs);
    }
  }
}

// ---------------- final GEMM + fused output head ----------------
__global__ void k_gemm_out(const ushort_t* __restrict__ A, const ushort_t* __restrict__ Bt,
                           const float* __restrict__ bias, const float* __restrict__ Wo2,
                           const float* __restrict__ bo2, const float* __restrict__ x,
                           float* __restrict__ out, int n){
  int wv = threadIdx.x >> 6, lane = threadIdx.x & 63;
  int r0 = blockIdx.x * 64 + wv * 16;
  int lr = lane & 15, lk = lane >> 4;
  int arow = r0 + lr; if (arow >= n) arow = n - 1;
  const ushort_t* Ap = A + (size_t)arow * HID + lk * 8;
  bf16x8 a[4];
  #pragma unroll
  for (int kb = 0; kb < 4; ++kb) a[kb] = *(const bf16x8*)(Ap + kb * 32);
  f32x4 acc[8];
  #pragma unroll
  for (int t = 0; t < 8; ++t) acc[t] = (f32x4){0.f, 0.f, 0.f, 0.f};
  #pragma unroll
  for (int t = 0; t < 8; ++t){
    const ushort_t* Bp = Bt + (size_t)(t * 16 + lr) * HID + lk * 8;
    #pragma unroll
    for (int kb = 0; kb < 4; ++kb){
      bf16x8 b = *(const bf16x8*)(Bp + kb * 32);
      acc[t] = __builtin_amdgcn_mfma_f32_16x16x32_bf16(a[kb], b, acc[t], 0, 0, 0);
    }
  }
  #pragma unroll
  for (int j = 0; j < 4; ++j){
    float p0 = 0.f, p1 = 0.f, p2 = 0.f;
    #pragma unroll
    for (int t = 0; t < 8; ++t){
      int col = t * 16 + lr;
      float v = leaky(acc[t][j] + bias[col]);
      p0 += v * Wo2[col * 3 + 0];
      p1 += v * Wo2[col * 3 + 1];
      p2 += v * Wo2[col * 3 + 2];
    }
    #pragma unroll
    for (int off = 1; off < 16; off <<= 1){
      p0 += __shfl_xor(p0, off);
      p1 += __shfl_xor(p1, off);
      p2 += __shfl_xor(p2, off);
    }
    int rr = r0 + lk * 4 + j;
    if (lr == 0 && rr < n){
      out[rr * 3 + 0] = x[rr * DIN + 15] + p0 + bo2[0];
      out[rr * 3 + 1] = x[rr * DIN + 16] + p1 + bo2[1];
      out[rr * 3 + 2] = x[rr * DIN + 17] + p2 + bo2[2];
    }
  }
}

// ---------------- single-head aggregation + optional fused mh scores ----------------
__global__ void k_agg_sh(const int* __restrict__ rowptr, const int* __restrict__ cols,
                         const float* __restrict__ ssrc, const float* __restrict__ sdst,
                         const ushort_t* __restrict__ hv, const ushort_t* __restrict__ resid,
                         const float* __restrict__ bng, const float* __restrict__ bnb,
                         const float* __restrict__ bnm, const float* __restrict__ bnv,
                         const float* __restrict__ masrc, const float* __restrict__ madst,
                         float* __restrict__ ossrc, float* __restrict__ osdst,
                         ushort_t* __restrict__ out, int n, int nbk){
  __shared__ int   s_cv[4][64];
  __shared__ float s_ex[4][64];
  int wid = threadIdx.x >> 6;
  int node = blockIdx.x * 4 + wid;
  if (node >= n) return;
  int lane = threadIdx.x & 63;
  const unsigned* hv32 = (const unsigned*)hv;
  int s = rowptr[node * nbk], e = rowptr[(node + 1) * nbk];
  float sq = ssrc[node];
  float ssum = 0.f, a0 = 0.f, a1 = 0.f;
  for (int j0 = s; j0 < e; j0 += 64){
    int len = min(64, e - j0);
    int cv = 0; float ex = 0.f;
    if (lane < len){
      cv = cols[j0 + lane];
      ex = __expf(leaky(sq + sdst[cv]));
    }
    ssum += ex;
    s_cv[wid][lane] = cv;
    s_ex[wid][lane] = ex;
    int k = 0;
    for (; k + 16 <= len; k += 16){
      unsigned p[16]; float l[16];
      #pragma unroll
      for (int u = 0; u < 16; ++u){
        int c = s_cv[wid][k + u];
        l[u] = s_ex[wid][k + u];
        p[u] = hv32[c * 64 + lane];
      }
      #pragma unroll
      for (int u = 0; u < 16; ++u){
        a0 += l[u] * bf_lo(p[u]); a1 += l[u] * bf_hi(p[u]);
      }
    }
    for (; k + 8 <= len; k += 8){
      unsigned p[8]; float l[8];
      #pragma unroll
      for (int u = 0; u < 8; ++u){
        int c = s_cv[wid][k + u];
        l[u] = s_ex[wid][k + u];
        p[u] = hv32[c * 64 + lane];
      }
      #pragma unroll
      for (int u = 0; u < 8; ++u){
        a0 += l[u] * bf_lo(p[u]); a1 += l[u] * bf_hi(p[u]);
      }
    }
    for (; k + 4 <= len; k += 4){
      unsigned p[4]; float l[4];
      #pragma unroll
      for (int u = 0; u < 4; ++u){
        int c = s_cv[wid][k + u];
        l[u] = s_ex[wid][k + u];
        p[u] = hv32[c * 64 + lane];
      }
      #pragma unroll
      for (int u = 0; u < 4; ++u){
        a0 += l[u] * bf_lo(p[u]); a1 += l[u] * bf_hi(p[u]);
      }
    }
    for (; k < len; ++k){
      int c = s_cv[wid][k];
      float l = s_ex[wid][k];
      unsigned p = hv32[c * 64 + lane];
      a0 += l * bf_lo(p); a1 += l * bf_hi(p);
    }
  }
  ssum = wred_sum(ssum);
  float inv = 1.f / (ssum + 1e-16f);
  a0 *= inv; a1 *= inv;
  int d0 = 2 * lane, d1 = 2 * lane + 1;
  float v0 = (a0 - bnm[d0]) * rsqrtf(bnv[d0] + BN_EPS) * bng[d0] + bnb[d0];
  float v1 = (a1 - bnm[d1]) * rsqrtf(bnv[d1] + BN_EPS) * bng[d1] + bnb[d1];
  if (resid){
    unsigned rv = *(const unsigned*)&resid[node * HID + d0];
    v0 += bf_lo(rv); v1 += bf_hi(rv);
  }
  float o0 = leaky(v0), o1 = leaky(v1);
  *(unsigned*)&out[node * HID + d0] = packbf(o0, o1);
  if (ossrc){
    #pragma unroll
    for (int h = 0; h < 4; ++h){
      float ps = o0 * masrc[h * HID + d0] + o1 * masrc[h * HID + d1];
      float pd = o0 * madst[h * HID + d0] + o1 * madst[h * HID + d1];
      ps = wred_sum(ps);
      pd = wred_sum(pd);
      if (lane == 0){ ossrc[node * 4 + h] = ps; osdst[node * 4 + h] = pd; }
    }
  }
}

// ---------------- multi-head aggregation + fused layer-2 sh scores ----------------
__global__ void k_agg_mh(const int* __restrict__ rowptr, const int* __restrict__ cols,
                         const float* __restrict__ ssrc, const float* __restrict__ sdst,
                         const ushort_t* __restrict__ hv,
                         const float* __restrict__ bng, const float* __restrict__ bnb,
                         const float* __restrict__ bnm, const float* __restrict__ bnv,
                         const float* __restrict__ sasrc, const float* __restrict__ sadst,
                         float* __restrict__ ossrc, float* __restrict__ osdst,
                         ushort_t* __restrict__ out, int n, int nbk){
  __shared__ int    s_cv[4][64];
  __shared__ float4 s_ex[4][64];
  int wid = threadIdx.x >> 6;
  int node = blockIdx.x * 4 + wid;
  if (node >= n) return;
  int lane = threadIdx.x & 63;
  const unsigned* hv32 = (const unsigned*)hv;
  int s = rowptr[node * nbk], e = rowptr[(node + 1) * nbk];
  const float4 sq = *(const float4*)&ssrc[node * 4];
  int hd = lane >> 4;
  float s0 = 0.f, s1 = 0.f, s2 = 0.f, s3 = 0.f;
  float a0 = 0.f, a1 = 0.f;
  const float* exw = &s_ex[wid][0].x;
  for (int j0 = s; j0 < e; j0 += 64){
    int len = min(64, e - j0);
    int cv = 0;
    float e0 = 0.f, e1 = 0.f, e2 = 0.f, e3 = 0.f;
    if (lane < len){
      cv = cols[j0 + lane];
      float4 kd = *(const float4*)&sdst[cv * 4];
      e0 = __expf(leaky(sq.x + kd.x)); e1 = __expf(leaky(sq.y + kd.y));
      e2 = __expf(leaky(sq.z + kd.z)); e3 = __expf(leaky(sq.w + kd.w));
    }
    s0 += e0; s1 += e1; s2 += e2; s3 += e3;
    s_cv[wid][lane] = cv;
    s_ex[wid][lane] = make_float4(e0, e1, e2, e3);
    int k = 0;
    for (; k + 16 <= len; k += 16){
      unsigned p[16]; float l[16];
      #pragma unroll
      for (int u = 0; u < 16; ++u){
        int c = s_cv[wid][k + u];
        l[u] = exw[(k + u) * 4 + hd];
        p[u] = hv32[c * 64 + lane];
      }
      #pragma unroll
      for (int u = 0; u < 16; ++u){
        a0 += l[u] * bf_lo(p[u]); a1 += l[u] * bf_hi(p[u]);
      }
    }
    for (; k + 8 <= len; k += 8){
      unsigned p[8]; float l[8];
      #pragma unroll
      for (int u = 0; u < 8; ++u){
        int c = s_cv[wid][k + u];
        l[u] = exw[(k + u) * 4 + hd];
        p[u] = hv32[c * 64 + lane];
      }
      #pragma unroll
      for (int u = 0; u < 8; ++u){
        a0 += l[u] * bf_lo(p[u]); a1 += l[u] * bf_hi(p[u]);
      }
    }
    for (; k + 4 <= len; k += 4){
      unsigned p[4]; float l[4];
      #pragma unroll
      for (int u = 0; u < 4; ++u){
        int c = s_cv[wid][k + u];
        l[u] = exw[(k + u) * 4 + hd];
        p[u] = hv32[c * 64 + lane];
      }
      #pragma unroll
      for (int u = 0; u < 4; ++u){
        a0 += l[u] * bf_lo(p[u]); a1 += l[u] * bf_hi(p[u]);
      }
    }
    for (; k < len; ++k){
      int c = s_cv[wid][k];
      float l = exw[k * 4 + hd];
      unsigned p = hv32[c * 64 + lane];
      a0 += l * bf_lo(p); a1 += l * bf_hi(p);
    }
  }
  s0 = wred_sum(s0); s1 = wred_sum(s1);
  s2 = wred_sum(s2); s3 = wred_sum(s3);
  float i0 = 1.f / (s0 + 1e-16f), i1 = 1.f / (s1 + 1e-16f);
  float i2 = 1.f / (s2 + 1e-16f), i3 = 1.f / (s3 + 1e-16f);
  float ih = sel4(i0, i1, i2, i3, hd);
  a0 *= ih; a1 *= ih;
  int d0 = 2 * lane, d1 = 2 * lane + 1;
  float v0 = (a0 - bnm[d0]) * rsqrtf(bnv[d0] + BN_EPS) * bng[d0] + bnb[d0];
  float v1 = (a1 - bnm[d1]) * rsqrtf(bnv[d1] + BN_EPS) * bng[d1] + bnb[d1];
  float o0 = leaky(v0), o1 = leaky(v1);
  *(unsigned*)&out[node * HID + d0] = packbf(o0, o1);
  float ps = o0 * sasrc[d0] + o1 * sasrc[d1];
  float pd = o0 * sadst[d0] + o1 * sadst[d1];
  ps = wred_sum(ps);
  pd = wred_sum(pd);
  if (lane == 0){ ossrc[node] = ps; osdst[node] = pd; }
}

extern "C" void kernel_launch(void* const* d_in, const int* in_sizes, int n_in,
                              void* d_out, int out_size, void* d_ws, size_t ws_size,
                              hipStream_t stream){
  const float* x       = (const float*)d_in[0];
  const int*   ei      = (const int*)  d_in[1];
  const float* W_in    = (const float*)d_in[2];
  const float* b_in    = (const float*)d_in[3];
  const float* W_agg   = (const float*)d_in[4];
  const float* b_agg   = (const float*)d_in[5];
  const float* sh_Wv   = (const float*)d_in[6];
  const float* sh_b    = (const float*)d_in[7];
  const float* sh_asrc = (const float*)d_in[8];
  const float* sh_adst = (const float*)d_in[9];
  const float* mh_Wv   = (const float*)d_in[10];
  const float* mh_b    = (const float*)d_in[11];
  const float* mh_asrc = (const float*)d_in[12];
  const float* mh_adst = (const float*)d_in[13];
  const float* bn_g    = (const float*)d_in[14];
  const float* bn_bt   = (const float*)d_in[15];
  const float* bn_m    = (const float*)d_in[16];
  const float* bn_v    = (const float*)d_in[17];
  const float* W_o1    = (const float*)d_in[18];
  const float* b_o1    = (const float*)d_in[19];
  const float* W_o2    = (const float*)d_in[20];
  const float* b_o2    = (const float*)d_in[21];
  float* out = (float*)d_out;

  const int N = in_sizes[0] / DIN;
  const int E = in_sizes[1] / 2;
  const int* row = ei;
  const int* col = ei + E;
  const int NBK = (N + (1 << BSH) - 1) >> BSH;   // buckets per node
  const int NK = N * NBK;                         // total CSR keys

  char* w = (char*)d_ws;
  size_t off = 0;
  auto alloc = [&](size_t bytes) -> void* {
    void* p = w + off;
    off = (off + bytes + 255) & ~(size_t)255;
    return p;
  };
  int*      tmp    = (int*)     alloc((size_t)NK * 4);
  int*      rowptr = (int*)     alloc((size_t)(NK + 1) * 4);
  int*      cols_s = (int*)     alloc((size_t)E * 4);
  int*      rank   = (int*)     alloc((size_t)E * 4);
  int*      bsum   = (int*)     alloc((size_t)1024 * 4);
  float*    ssrcA  = (float*)   alloc((size_t)N * 4);
  float*    sdstA  = (float*)   alloc((size_t)N * 4);
  float*    ssrcB  = (float*)   alloc((size_t)N * 4 * 4);
  float*    sdstB  = (float*)   alloc((size_t)N * 4 * 4);
  ushort_t* wt0    = (ushort_t*)alloc((size_t)HID * HID * 2);
  ushort_t* wt1    = (ushort_t*)alloc((size_t)HID * HID * 2);
  ushort_t* wt2    = (ushort_t*)alloc((size_t)HID * HID * 2);
  ushort_t* wt3    = (ushort_t*)alloc((size_t)HID * HID * 2);
  ushort_t* b0     = (ushort_t*)alloc((size_t)N * HID * 2);
  ushort_t* b1     = (ushort_t*)alloc((size_t)N * HID * 2);
  ushort_t* hvb    = (ushort_t*)alloc((size_t)N * HID * 2);

  const int eb = (E + 255) / 256;
  const int nb4 = (N + 3) / 4;
  const int gb = (N + 63) / 64;
  const int nsb = (NK + SCHUNK - 1) / SCHUNK;

  // bucketed CSR build (one atomic pass)
  hipMemsetAsync(tmp, 0, (size_t)NK * 4, stream);
  k_deg_rank<<<eb, 256, 0, stream>>>(row, col, tmp, rank, E, NBK);
  k_scan1<<<nsb, 256, 0, stream>>>(tmp, bsum, NK);
  k_scan2<<<1, 64, 0, stream>>>(bsum, nsb);
  k_scan3<<<nsb, 256, 0, stream>>>(tmp, bsum, rowptr, NK);
  k_scatter<<<eb, 256, 0, stream>>>(row, col, rowptr, rank, cols_s, E, NBK);

  // fused weight prep (bf16, transposed)
  k_wtprep<<<256, 256, 0, stream>>>(sh_Wv, mh_Wv, W_o1, wt0, wt1, wt2, wt3);

  // fused nmean + input projection (+layer0 sh scores) -> b0 (bf16)
  k_nmean_hin<<<nb4, 256, 0, stream>>>(x, rowptr, cols_s, W_in, b_in, W_agg, b_agg,
                                       sh_asrc, sh_adst, ssrcA, sdstA, b0, N, NBK);

  // layer 0: single-head, residual b0, bn[0] -> b1 (+mh scores)
  k_gemm_mfma<<<gb, 256, 0, stream>>>(b0, wt0, sh_b, hvb, N);
  k_agg_sh<<<nb4, 256, 0, stream>>>(rowptr, cols_s, ssrcA, sdstA, hvb, b0,
                                    bn_g, bn_bt, bn_m, bn_v,
                                    mh_asrc, mh_adst, ssrcB, sdstB, b1, N, NBK);

  // layer 1: multi-head, bn[1], no residual -> b0 (+layer2 sh scores)
  k_gemm_mfma<<<gb, 256, 0, stream>>>(b1, wt1, mh_b, hvb, N);
  k_agg_mh<<<nb4, 256, 0, stream>>>(rowptr, cols_s, ssrcB, sdstB, hvb,
                                    bn_g + HID, bn_bt + HID, bn_m + HID, bn_v + HID,
                                    sh_asrc + HID, sh_adst + HID, ssrcA, sdstA, b0, N, NBK);

  // layer 2: single-head, residual b0, bn[2] -> b1
  k_gemm_mfma<<<gb, 256, 0, stream>>>(b0, wt2, sh_b + HID, hvb, N);
  k_agg_sh<<<nb4, 256, 0, stream>>>(rowptr, cols_s, ssrcA, sdstA, hvb, b0,
                                    bn_g + 2 * HID, bn_bt + 2 * HID, bn_m + 2 * HID, bn_v + 2 * HID,
                                    nullptr, nullptr, nullptr, nullptr, b1, N, NBK);

  // output head fused into final GEMM
  k_gemm_out<<<gb, 256, 0, stream>>>(b1, wt3, b_o1, W_o2, b_o2, x, out, N);
}